// Round 1
// baseline (1214.902 us; speedup 1.0000x reference)
//
#include <hip/hip_runtime.h>
#include <math.h>

#ifndef M_PI
#define M_PI 3.14159265358979323846
#endif

#define NFFT  512
#define NBINS 257
#define HOP   160
#define NBM   256     // mean-reduction stage-1 blocks
#define NBLK_MAX 512  // stft partial blocks

__device__ __forceinline__ float wave_reduce(float v) {
    for (int off = 32; off > 0; off >>= 1) v += __shfl_down(v, off, 64);
    return v;
}

// ---------------- stage 1: per-block partial sums for the channel means ----
__global__ __launch_bounds__(256) void mean_partial_kernel(
        const float* __restrict__ x0, const float* __restrict__ x1,
        float* __restrict__ part, int n, int nbm)
{
    int tid = threadIdx.x;
    float s0 = 0.f, s1 = 0.f;
    for (int i = blockIdx.x * blockDim.x + tid; i < n; i += blockDim.x * gridDim.x) {
        s0 += x0[i];
        s1 += x1[i];
    }
    __shared__ float red[4][2];
    s0 = wave_reduce(s0); s1 = wave_reduce(s1);
    int lane = tid & 63, w = tid >> 6;
    if (lane == 0) { red[w][0] = s0; red[w][1] = s1; }
    __syncthreads();
    if (tid == 0) {
        part[blockIdx.x]        = red[0][0] + red[1][0] + red[2][0] + red[3][0];
        part[nbm + blockIdx.x]  = red[0][1] + red[1][1] + red[2][1] + red[3][1];
    }
}

// ---------------- stage 2: finish means (scaled by 1/32768) ----------------
__global__ __launch_bounds__(256) void mean_final_kernel(
        const float* __restrict__ part, float* __restrict__ means, int n, int nbm)
{
    int tid = threadIdx.x;
    float v0 = (tid < nbm) ? part[tid]       : 0.f;
    float v1 = (tid < nbm) ? part[nbm + tid] : 0.f;
    __shared__ float red[4][2];
    v0 = wave_reduce(v0); v1 = wave_reduce(v1);
    int lane = tid & 63, w = tid >> 6;
    if (lane == 0) { red[w][0] = v0; red[w][1] = v1; }
    __syncthreads();
    if (tid == 0) {
        float s0 = red[0][0] + red[1][0] + red[2][0] + red[3][0];
        float s1 = red[0][1] + red[1][1] + red[2][1] + red[3][1];
        float inv = 1.0f / ((float)n * 32768.0f);
        means[0] = s0 * inv;
        means[1] = s1 * inv;
    }
}

// ---------------- stage 3: STFT + weighted covariance accumulation ---------
// thread k (0..255) owns DFT bin k; bin 256 (Nyquist, real) via block reduce.
#define DFT_STEP(av, bv)                                            \
    xr0 = fmaf((av), c, xr0); xi0 = fmaf((av), s, xi0);             \
    xr1 = fmaf((bv), c, xr1); xi1 = fmaf((bv), s, xi1);             \
    { float t1 = s * sd; float t2 = c * sd;                         \
      float cn = fmaf(c, cd, -t1); s = fmaf(s, cd, t2); c = cn; }

__global__ __launch_bounds__(256) void stft_kernel(
        const float* __restrict__ x0, const float* __restrict__ x1,
        const float* __restrict__ means, float* __restrict__ partials,
        int nframes, int fpb, float invS, float kslope)
{
    __shared__ __align__(16) float win[NFFT];
    __shared__ __align__(16) float wz0[NFFT];
    __shared__ __align__(16) float wz1[NFFT];
    __shared__ float red[4][2];

    int tid = threadIdx.x;
    for (int j = tid; j < NFFT; j += 256) {
        win[j] = 0.5f - 0.5f * cosf((float)(2.0 * M_PI / 512.0) * (float)j);
    }
    float m0 = means[0], m1 = means[1];
    const float k15 = 1.0f / 32768.0f;

    int k = tid;
    float cd, sd;
    sincosf((float)(-2.0 * M_PI / 512.0) * (float)k, &sd, &cd);

    float r00 = 0.f, r11 = 0.f, r01r = 0.f, r01i = 0.f;
    float q00 = 0.f, q11 = 0.f, q01 = 0.f;   // bin-256 accum (thread 0 only)

    int f0 = blockIdx.x * fpb;
    int f1 = f0 + fpb; if (f1 > nframes) f1 = nframes;

    const float4* a4 = (const float4*)wz0;
    const float4* b4 = (const float4*)wz1;

    for (int f = f0; f < f1; ++f) {
        int base = f * HOP;
        __syncthreads();   // protect wz* from previous frame's readers
        float v0 = 0.f, v1 = 0.f;
        for (int n = tid; n < NFFT; n += 256) {
            int g = base + n;
            float xa = x0[g], xb = x1[g];
            float pa = (g > 0) ? x0[g - 1] : 0.f;
            float pb = (g > 0) ? x1[g - 1] : 0.f;
            float wa  = fmaf(xa, k15, -m0);
            float wpa = fmaf(pa, k15, -m0);
            float wb  = fmaf(xb, k15, -m1);
            float wpb = fmaf(pb, k15, -m1);
            float ya = (g == 0) ? wa : fmaf(-0.97f, wpa, wa);
            float yb = (g == 0) ? wb : fmaf(-0.97f, wpb, wb);
            float za = ya * win[n];
            float zb = yb * win[n];
            wz0[n] = za; wz1[n] = zb;
            float sgn = (n & 1) ? -1.f : 1.f;
            v0 = fmaf(sgn, za, v0);
            v1 = fmaf(sgn, zb, v1);
        }
        v0 = wave_reduce(v0); v1 = wave_reduce(v1);
        int lane = tid & 63, w = tid >> 6;
        if (lane == 0) { red[w][0] = v0; red[w][1] = v1; }
        __syncthreads();

        float wt = expf(fmaf(kslope, (float)f, -2.0f)) * invS;

        if (tid == 0) {
            float X0 = red[0][0] + red[1][0] + red[2][0] + red[3][0];
            float X1 = red[0][1] + red[1][1] + red[2][1] + red[3][1];
            q00 = fmaf(wt, X0 * X0, q00);
            q11 = fmaf(wt, X1 * X1, q11);
            q01 = fmaf(wt, X0 * X1, q01);
        }

        // direct DFT of bin k via rotation recurrence, resync every 64 steps
        float xr0 = 0.f, xi0 = 0.f, xr1 = 0.f, xi1 = 0.f;
        for (int j = 0; j < 8; ++j) {
            float ang = (float)(-M_PI / 4.0) * (float)((k * j) & 7);
            float c, s;
            sincosf(ang, &s, &c);
            #pragma unroll
            for (int q = 0; q < 16; ++q) {
                float4 a = a4[j * 16 + q];
                float4 b = b4[j * 16 + q];
                DFT_STEP(a.x, b.x)
                DFT_STEP(a.y, b.y)
                DFT_STEP(a.z, b.z)
                DFT_STEP(a.w, b.w)
            }
        }
        r00  = fmaf(wt, fmaf(xr0, xr0, xi0 * xi0), r00);
        r11  = fmaf(wt, fmaf(xr1, xr1, xi1 * xi1), r11);
        r01r = fmaf(wt, fmaf(xr0, xr1, xi0 * xi1), r01r);
        r01i = fmaf(wt, fmaf(xi0, xr1, -(xr0 * xi1)), r01i);
    }

    float* pb = partials + (size_t)blockIdx.x * (4 * NBINS);
    pb[0 * NBINS + k] = r00;
    pb[1 * NBINS + k] = r11;
    pb[2 * NBINS + k] = r01r;
    pb[3 * NBINS + k] = r01i;
    if (tid == 0) {
        pb[0 * NBINS + 256] = q00;
        pb[1 * NBINS + 256] = q11;
        pb[2 * NBINS + 256] = q01;
        pb[3 * NBINS + 256] = 0.f;
    }
}

// ---------------- stage 4: reduce partials, MVDR scoring, argmax -----------
__global__ __launch_bounds__(512) void score_kernel(
        const float* __restrict__ partials, int nblk, float* __restrict__ out)
{
    __shared__ float Rsh[4 * NBINS];
    __shared__ float Ssh[NBINS], Qr[NBINS], Qi[NBINS], FW[NBINS];
    __shared__ float scores[181];
    __shared__ float invcw_sh;

    int tid = threadIdx.x;
    for (int slot = tid; slot < 4 * NBINS; slot += 512) {
        float s = 0.f;
        #pragma unroll 4
        for (int b = 0; b < nblk; ++b) s += partials[(size_t)b * (4 * NBINS) + slot];
        Rsh[slot] = s;
    }
    __syncthreads();

    if (tid < NBINS) {
        float R00  = Rsh[0 * NBINS + tid];
        float R11  = Rsh[1 * NBINS + tid];
        float R01r = Rsh[2 * NBINS + tid];
        float R01i = Rsh[3 * NBINS + tid];
        float trace = (R00 + R11) * 0.5f;
        float det = R00 * R11 - (R01r * R01r + R01i * R01i) + 1e-6f * trace;
        float inv_det = 1.0f / det;
        Ssh[tid] = R11 * inv_det + R00 * inv_det;   // iR00 + iR11
        Qr[tid]  = -R01r * inv_det;
        Qi[tid]  = -R01i * inv_det;
        // FREQ_W (unnormalized), replicating the numpy fp32 recipe
        float fq = 31.25f * (float)tid;
        float wl = 343.0f / (fq + 1e-6f);
        float sr = 0.05f / wl;
        float spatial = 1.0f / (1.0f + expf(-4.0f * (sr - 0.1f)));
        float d = fq - (float)(16000.0 / 6.0);
        float fw = 1.0f - expf(-(d * d) / (float)(2.0 * 4000.0 * 4000.0));
        float alias = (sr < 0.5f) ? 1.0f : expf(-2.0f * (sr - 0.5f) * (sr - 0.5f));
        FW[tid] = spatial * fw * alias;
    }
    __syncthreads();
    if (tid == 0) {
        float s = 0.f;
        for (int i = 0; i < NBINS; ++i) s += FW[i];
        invcw_sh = 1.0f / (s + 1e-6f);
    }
    __syncthreads();
    float invcw = invcw_sh;

    if (tid < 181) {
        float rad = (float)tid * (float)(M_PI / 180.0);
        float tau = -(0.05f * cosf(rad)) / 343.0f;
        float t2  = (float)(2.0 * M_PI) * tau;
        float geo = 0.f, ari = 0.f;
        float m = -1e30f, se = 0.f, pe = 0.f;
        for (int kk = 0; kk < NBINS; ++kk) {
            float fq = 31.25f * (float)kk;
            float phase = t2 * fq;
            float cr, ci;
            sincosf(phase, &ci, &cr);
            float t  = Qr[kk] * cr + Qi[kk] * ci;
            float qf = Ssh[kk] + t + t;
            float mv = 1.0f / (qf + 1e-6f);
            float fwv = FW[kk] * invcw;
            geo = fmaf(logf(mv + 1e-6f), fwv, geo);
            ari = fmaf(mv, fwv, ari);
            float x = mv + mv;           // softmax logits = 2*mvdr
            if (x > m) {
                float sc = expf(m - x);
                se = fmaf(se, sc, 1.0f);
                pe = fmaf(pe, sc, mv * fwv);
                m = x;
            } else {
                float e = expf(x - m);
                se += e;
                pe = fmaf(mv * fwv, e, pe);
            }
        }
        float peak = pe / se;
        scores[tid] = 0.5f * expf(geo) + 0.3f * ari + 0.2f * peak;
    }
    __syncthreads();
    if (tid == 0) {
        int best = 0; float bv = scores[0];
        for (int a = 1; a < 181; ++a) {
            if (scores[a] > bv) { bv = scores[a]; best = a; }
        }
        out[0] = (float)best;   // ANGLE_GRID is exactly 0..180 step 1
    }
}

extern "C" void kernel_launch(void* const* d_in, const int* in_sizes, int n_in,
                              void* d_out, int out_size, void* d_ws, size_t ws_size,
                              hipStream_t stream) {
    const float* x0 = (const float*)d_in[0];
    const float* x1 = (const float*)d_in[1];
    float* out = (float*)d_out;
    int T = in_sizes[0];
    int nframes = (T - NFFT) / HOP + 1;

    // TEMPORAL normalization: sum over all MAXLEN=40000 entries (host, double)
    double S = 0.0;
    for (int j = 0; j < 40000; ++j) S += exp(-2.0 + 2.0 * (double)j / 39999.0);
    float invS = (float)(1.0 / S);
    float kslope = (float)(2.0 / 39999.0);

    float* ws       = (float*)d_ws;
    float* means    = ws;          // 2 floats
    float* mpart    = ws + 16;     // 2*NBM floats
    float* partials = ws + 1024;   // nblk * 4*NBINS floats

    size_t avail = (ws_size / 4 > 1024) ? (ws_size / 4 - 1024) : 0;
    int nblk = (int)(avail / (4 * NBINS));
    if (nblk > NBLK_MAX) nblk = NBLK_MAX;
    if (nblk < 1) nblk = 1;
    int fpb = (nframes + nblk - 1) / nblk;

    mean_partial_kernel<<<NBM, 256, 0, stream>>>(x0, x1, mpart, T, NBM);
    mean_final_kernel<<<1, 256, 0, stream>>>(mpart, means, T, NBM);
    stft_kernel<<<nblk, 256, 0, stream>>>(x0, x1, means, partials, nframes, fpb, invS, kslope);
    score_kernel<<<1, 512, 0, stream>>>(partials, nblk, out);
}

// Round 3
// 193.721 us; speedup vs baseline: 6.2714x; 6.2714x over previous
//
#include <hip/hip_runtime.h>
#include <math.h>

#ifndef M_PI
#define M_PI 3.14159265358979323846
#endif

#define HOP 160
#define NBM 256

__device__ __forceinline__ float wave_reduce(float v) {
    for (int off = 32; off > 0; off >>= 1) v += __shfl_down(v, off, 64);
    return v;
}

// 8-point complex DFT in registers, natural order, W8 = exp(-i*pi/4).
__device__ __forceinline__ void dft8(float* xr, float* xi) {
    const float s = 0.70710678118654752440f;
    float t0r = xr[0] + xr[4], t0i = xi[0] + xi[4];
    float t1r = xr[0] - xr[4], t1i = xi[0] - xi[4];
    float t2r = xr[2] + xr[6], t2i = xi[2] + xi[6];
    float t3r = xr[2] - xr[6], t3i = xi[2] - xi[6];
    float E0r = t0r + t2r, E0i = t0i + t2i;
    float E2r = t0r - t2r, E2i = t0i - t2i;
    float E1r = t1r + t3i, E1i = t1i - t3r;   // t1 - i*t3
    float E3r = t1r - t3i, E3i = t1i + t3r;   // t1 + i*t3
    float u0r = xr[1] + xr[5], u0i = xi[1] + xi[5];
    float u1r = xr[1] - xr[5], u1i = xi[1] - xi[5];
    float u2r = xr[3] + xr[7], u2i = xi[3] + xi[7];
    float u3r = xr[3] - xr[7], u3i = xi[3] - xi[7];
    float O0r = u0r + u2r, O0i = u0i + u2i;
    float O2r = u0r - u2r, O2i = u0i - u2i;
    float O1r = u1r + u3i, O1i = u1i - u3r;
    float O3r = u1r - u3i, O3i = u1i + u3r;
    float T1r = s * (O1r + O1i), T1i = s * (O1i - O1r);   // W8^1 * O1
    float T2r = O2i,             T2i = -O2r;              // -i * O2
    float T3r = s * (O3i - O3r), T3i = -s * (O3r + O3i);  // W8^3 * O3
    xr[0] = E0r + O0r; xi[0] = E0i + O0i;
    xr[4] = E0r - O0r; xi[4] = E0i - O0i;
    xr[1] = E1r + T1r; xi[1] = E1i + T1i;
    xr[5] = E1r - T1r; xi[5] = E1i - T1i;
    xr[2] = E2r + T2r; xi[2] = E2i + T2i;
    xr[6] = E2r - T2r; xi[6] = E2i - T2i;
    xr[3] = E3r + T3r; xi[3] = E3i + T3i;
    xr[7] = E3r - T3r; xi[7] = E3i - T3i;
}

__device__ __forceinline__ void cmul_t(float& zr, float& zi, float tr, float ti) {
    float r = zr * tr - zi * ti;
    float i = zr * ti + zi * tr;
    zr = r; zi = i;
}

// ---------------- channel means (2 stages) ----------------
__global__ __launch_bounds__(256) void mean_partial_kernel(
        const float* __restrict__ x0, const float* __restrict__ x1,
        float* __restrict__ part, int n, int nbm)
{
    int tid = threadIdx.x;
    float s0 = 0.f, s1 = 0.f;
    int n4 = n >> 2;
    const float4* x04 = (const float4*)x0;
    const float4* x14 = (const float4*)x1;
    for (int i = blockIdx.x * blockDim.x + tid; i < n4; i += blockDim.x * gridDim.x) {
        float4 a = x04[i], b = x14[i];
        s0 += (a.x + a.y) + (a.z + a.w);
        s1 += (b.x + b.y) + (b.z + b.w);
    }
    __shared__ float red[4][2];
    s0 = wave_reduce(s0); s1 = wave_reduce(s1);
    int lane = tid & 63, w = tid >> 6;
    if (lane == 0) { red[w][0] = s0; red[w][1] = s1; }
    __syncthreads();
    if (tid == 0) {
        part[blockIdx.x]       = red[0][0] + red[1][0] + red[2][0] + red[3][0];
        part[nbm + blockIdx.x] = red[0][1] + red[1][1] + red[2][1] + red[3][1];
    }
}

__global__ __launch_bounds__(256) void mean_final_kernel(
        const float* __restrict__ part, float* __restrict__ means, int n, int nbm)
{
    int tid = threadIdx.x;
    float v0 = (tid < nbm) ? part[tid]       : 0.f;
    float v1 = (tid < nbm) ? part[nbm + tid] : 0.f;
    __shared__ float red[4][2];
    v0 = wave_reduce(v0); v1 = wave_reduce(v1);
    int lane = tid & 63, w = tid >> 6;
    if (lane == 0) { red[w][0] = v0; red[w][1] = v1; }
    __syncthreads();
    if (tid == 0) {
        float s0 = red[0][0] + red[1][0] + red[2][0] + red[3][0];
        float s1 = red[0][1] + red[1][1] + red[2][1] + red[3][1];
        float inv = 1.0f / ((float)n * 32768.0f);
        means[0] = s0 * inv;
        means[1] = s1 * inv;
    }
}

// ---------------- STFT via wave-local radix-8^3 FFT + covariance -----------
// One wave = one frame per iteration. z = y0 + i*y1 packed complex FFT.
// n = n0 + 8*n1 + 64*n2 ; k = k2 + 8*k1 + 64*k0 ; lane roles: n0=l&7, hi=l>>3.
__global__ __launch_bounds__(256) void stft_fft_kernel(
        const float* __restrict__ x0, const float* __restrict__ x1,
        const float* __restrict__ means, float* __restrict__ partials,
        int nframes, int fpb, int nslots, float invS, float kslope)
{
    __shared__ float2 lbuf[4][512];
    const int tid = threadIdx.x;
    const int w = tid >> 6, l = tid & 63;
    float2* buf = lbuf[w];
    const int n0 = l & 7, hi = l >> 3;
    const int slot = blockIdx.x * 4 + w;

    // per-lane constants
    float winv[8];
#pragma unroll
    for (int j = 0; j < 8; ++j)
        winv[j] = 0.5f - 0.5f * cosf((float)(2.0 * M_PI / 512.0) * (float)(l + 64 * j));
    float t1r[8], t1i[8], t2r[8], t2i[8];
#pragma unroll
    for (int j = 0; j < 8; ++j) {
        float a1 = (float)(-2.0 * M_PI / 64.0) * (float)(j * hi);
        sincosf(a1, &t1i[j], &t1r[j]);
        float a2 = (float)(-2.0 * M_PI / 512.0) * (float)(j * l);
        sincosf(a2, &t2i[j], &t2r[j]);
    }

    const float m0 = means[0], m1 = means[1];
    const float k15 = 1.0f / 32768.0f;

    float acc[4][4];
#pragma unroll
    for (int t = 0; t < 4; ++t)
#pragma unroll
        for (int q = 0; q < 4; ++q) acc[t][q] = 0.f;
    float a256[4] = {0.f, 0.f, 0.f, 0.f};

    int f0 = blockIdx.x * fpb;
    int f1 = f0 + fpb; if (f1 > nframes) f1 = nframes;
    int ng = (f1 > f0) ? ((f1 - f0 + 3) >> 2) : 0;

    for (int g = 0; g < ng; ++g) {
        int f = f0 + g * 4 + w;
        bool live = (f < f1);
        int fc = live ? f : (nframes - 1);
        int base = fc * HOP;
        float wt = live ? expf(fmaf(kslope, (float)f, -2.0f)) * invS : 0.f;

        float zr[8], zi[8];
#pragma unroll
        for (int j = 0; j < 8; ++j) {
            int t = base + l + 64 * j;
            float a = x0[t], b = x1[t];
            float ap = (t > 0) ? x0[t - 1] : 0.f;
            float bp = (t > 0) ? x1[t - 1] : 0.f;
            float wa  = fmaf(a,  k15, -m0);
            float wb  = fmaf(b,  k15, -m1);
            float wpa = fmaf(ap, k15, -m0);
            float wpb = fmaf(bp, k15, -m1);
            float ya = (t == 0) ? wa : fmaf(-0.97f, wpa, wa);
            float yb = (t == 0) ? wb : fmaf(-0.97f, wpb, wb);
            zr[j] = ya * winv[j];
            zi[j] = yb * winv[j];
        }

        dft8(zr, zi);                    // over n2 -> regs k2

        // T1: element (n0,n1,k2) stored at c1 = n0 + 8*(n1^k2) + 64*k2
#pragma unroll
        for (int k2 = 0; k2 < 8; ++k2)
            buf[(l ^ (k2 << 3)) + 64 * k2] = make_float2(zr[k2], zi[k2]);
        __syncthreads();
#pragma unroll
        for (int j = 0; j < 8; ++j) {    // read reg n1=j: lane role (n0, k2=hi)
            float2 v = buf[n0 + 8 * (j ^ hi) + 64 * hi];
            zr[j] = v.x; zi[j] = v.y;
        }
#pragma unroll
        for (int j = 1; j < 8; ++j) cmul_t(zr[j], zi[j], t1r[j], t1i[j]);  // W64^{n1*k2}
        dft8(zr, zi);                    // over n1 -> regs k1

        // T2: element (n0,k2,k1) stored at c2 = k2 + 8*(k1^n0) + 64*n0
#pragma unroll
        for (int k1 = 0; k1 < 8; ++k1)
            buf[hi + 8 * ((k1 ^ n0) + 8 * n0)] = make_float2(zr[k1], zi[k1]);
        __syncthreads();
#pragma unroll
        for (int j = 0; j < 8; ++j) {    // read reg n0=j: lane role (k2=n0pos, k1=hi)
            float2 v = buf[n0 + 8 * ((hi ^ j) + 8 * j)];
            zr[j] = v.x; zi[j] = v.y;
        }
#pragma unroll
        for (int j = 1; j < 8; ++j) cmul_t(zr[j], zi[j], t2r[j], t2i[j]);  // W512^{n0*l}
        dft8(zr, zi);                    // over n0 -> regs k0: Z[l + 64*k0]

        // conjugate partner: P[r] = Z[(512 - (l+64r)) & 511]
        int pl = (64 - l) & 63;
        float prr[8], pri[8];
#pragma unroll
        for (int r = 0; r < 8; ++r) {
            float sr = __shfl(zr[7 - r], pl, 64);
            float si = __shfl(zi[7 - r], pl, 64);
            if (l == 0) { sr = zr[(8 - r) & 7]; si = zi[(8 - r) & 7]; }
            prr[r] = sr; pri[r] = si;
        }

        // separation + covariance, bins k = l + 64r (r<4) all < 256
#pragma unroll
        for (int r = 0; r < 4; ++r) {
            float X0r = 0.5f * (zr[r] + prr[r]);
            float X0i = 0.5f * (zi[r] - pri[r]);
            float X1r = 0.5f * (zi[r] + pri[r]);
            float X1i = 0.5f * (prr[r] - zr[r]);
            acc[0][r] = fmaf(wt, fmaf(X0r, X0r, X0i * X0i), acc[0][r]);
            acc[1][r] = fmaf(wt, fmaf(X1r, X1r, X1i * X1i), acc[1][r]);
            acc[2][r] = fmaf(wt, fmaf(X0r, X1r, X0i * X1i), acc[2][r]);
            acc[3][r] = fmaf(wt, fmaf(X0i, X1r, -(X0r * X1i)), acc[3][r]);
        }
        {   // bin 256 = lane 0 reg 4 (self-conjugate)
            float X0r = 0.5f * (zr[4] + prr[4]);
            float X0i = 0.5f * (zi[4] - pri[4]);
            float X1r = 0.5f * (zi[4] + pri[4]);
            float X1i = 0.5f * (prr[4] - zr[4]);
            a256[0] = fmaf(wt, fmaf(X0r, X0r, X0i * X0i), a256[0]);
            a256[1] = fmaf(wt, fmaf(X1r, X1r, X1i * X1i), a256[1]);
            a256[2] = fmaf(wt, fmaf(X0r, X1r, X0i * X1i), a256[2]);
            a256[3] = fmaf(wt, fmaf(X0i, X1r, -(X0r * X1i)), a256[3]);
        }
        __syncthreads();   // protect buf before next iteration's T1 writes
    }

    // store per-wave partials: layout [term][bin][slot]
#pragma unroll
    for (int t = 0; t < 4; ++t) {
#pragma unroll
        for (int r = 0; r < 4; ++r)
            partials[(size_t)(t * 257 + (l + 64 * r)) * nslots + slot] = acc[t][r];
        if (l == 0)
            partials[(size_t)(t * 257 + 256) * nslots + slot] = a256[t];
    }
}

// ---------------- reduce partials over slots ----------------
__global__ __launch_bounds__(256) void reduce_kernel(
        const float* __restrict__ partials, float* __restrict__ R, int nslots)
{
    int k = blockIdx.x;   // 0..256
    __shared__ float red[4];
    int tid = threadIdx.x, lane = tid & 63, w = tid >> 6;
    for (int t = 0; t < 4; ++t) {
        const float* p = partials + (size_t)(t * 257 + k) * nslots;
        float s = 0.f;
        for (int i = tid; i < nslots; i += 256) s += p[i];
        s = wave_reduce(s);
        if (lane == 0) red[w] = s;
        __syncthreads();
        if (tid == 0) R[t * 257 + k] = red[0] + red[1] + red[2] + red[3];
        __syncthreads();
    }
}

// ---------------- MVDR scoring + argmax ----------------
__global__ __launch_bounds__(256) void score_kernel(
        const float* __restrict__ R, float* __restrict__ out)
{
    __shared__ float Ssh[257], Qr[257], Qi[257], FW[257];
    __shared__ float scores[181];
    __shared__ float invcw_sh;
    int tid = threadIdx.x;

    for (int k = tid; k < 257; k += 256) {
        float R00  = R[0 * 257 + k];
        float R11  = R[1 * 257 + k];
        float R01r = R[2 * 257 + k];
        float R01i = R[3 * 257 + k];
        float trace = (R00 + R11) * 0.5f;
        float det = R00 * R11 - (R01r * R01r + R01i * R01i) + 1e-6f * trace;
        float inv_det = 1.0f / det;
        Ssh[k] = R11 * inv_det + R00 * inv_det;
        Qr[k]  = -R01r * inv_det;
        Qi[k]  = -R01i * inv_det;
        float fq = 31.25f * (float)k;
        float wl = 343.0f / (fq + 1e-6f);
        float sr = 0.05f / wl;
        float spatial = 1.0f / (1.0f + expf(-4.0f * (sr - 0.1f)));
        float d = fq - (float)(16000.0 / 6.0);
        float fw = 1.0f - expf(-(d * d) / (float)(2.0 * 4000.0 * 4000.0));
        float alias = (sr < 0.5f) ? 1.0f : expf(-2.0f * (sr - 0.5f) * (sr - 0.5f));
        FW[k] = spatial * fw * alias;
    }
    __syncthreads();
    if (tid == 0) {
        float s = 0.f;
        for (int i = 0; i < 257; ++i) s += FW[i];
        invcw_sh = 1.0f / (s + 1e-6f);
    }
    __syncthreads();
    float invcw = invcw_sh;

    if (tid < 181) {
        float rad = (float)tid * (float)(M_PI / 180.0);
        float tau = -(0.05f * cosf(rad)) / 343.0f;
        float t2  = (float)(2.0 * M_PI) * tau;
        float geo = 0.f, ari = 0.f;
        float m = -1e30f, se = 0.f, pe = 0.f;
        for (int kk = 0; kk < 257; ++kk) {
            float fq = 31.25f * (float)kk;
            float phase = t2 * fq;
            float cr, ci;
            sincosf(phase, &ci, &cr);
            float t  = Qr[kk] * cr + Qi[kk] * ci;
            float qf = Ssh[kk] + t + t;
            float mv = 1.0f / (qf + 1e-6f);
            float fwv = FW[kk] * invcw;
            geo = fmaf(logf(mv + 1e-6f), fwv, geo);
            ari = fmaf(mv, fwv, ari);
            float x = mv + mv;
            if (x > m) {
                float sc = expf(m - x);
                se = fmaf(se, sc, 1.0f);
                pe = fmaf(pe, sc, mv * fwv);
                m = x;
            } else {
                float e = expf(x - m);
                se += e;
                pe = fmaf(mv * fwv, e, pe);
            }
        }
        float peak = pe / se;
        scores[tid] = 0.5f * expf(geo) + 0.3f * ari + 0.2f * peak;
    }
    __syncthreads();
    if (tid == 0) {
        int best = 0; float bv = scores[0];
        for (int a = 1; a < 181; ++a)
            if (scores[a] > bv) { bv = scores[a]; best = a; }
        out[0] = (float)best;
    }
}

extern "C" void kernel_launch(void* const* d_in, const int* in_sizes, int n_in,
                              void* d_out, int out_size, void* d_ws, size_t ws_size,
                              hipStream_t stream) {
    const float* x0 = (const float*)d_in[0];
    const float* x1 = (const float*)d_in[1];
    float* out = (float*)d_out;
    int T = in_sizes[0];
    int nframes = (T - 512) / HOP + 1;

    // TEMPORAL normalization: sum over all 40000 entries (host, double)
    double S = 0.0;
    for (int j = 0; j < 40000; ++j) S += exp(-2.0 + 2.0 * (double)j / 39999.0);
    float invS = (float)(1.0 / S);
    float kslope = (float)(2.0 / 39999.0);

    float* ws = (float*)d_ws;
    float* means    = ws;           // 2 floats
    float* mpart    = ws + 16;      // 2*NBM floats
    float* Rbuf     = ws + 600;     // 4*257 floats
    float* partials = ws + 2048;    // 4*257*nslots floats

    long availf = (long)(ws_size / 4) - 2048;
    int nblocks = (int)(availf / (4 * 257 * 4));
    if (nblocks > 1024) nblocks = 1024;
    if (nblocks < 1) nblocks = 1;
    int nslots = nblocks * 4;
    int fpb = (nframes + nblocks - 1) / nblocks;

    mean_partial_kernel<<<NBM, 256, 0, stream>>>(x0, x1, mpart, T, NBM);
    mean_final_kernel<<<1, 256, 0, stream>>>(mpart, means, T, NBM);
    stft_fft_kernel<<<nblocks, 256, 0, stream>>>(x0, x1, means, partials,
                                                 nframes, fpb, nslots, invS, kslope);
    reduce_kernel<<<257, 256, 0, stream>>>(partials, Rbuf, nslots);
    score_kernel<<<1, 256, 0, stream>>>(Rbuf, out);
}

// Round 4
// 84.795 us; speedup vs baseline: 14.3276x; 2.2846x over previous
//
#include <hip/hip_runtime.h>
#include <math.h>

#ifndef M_PI
#define M_PI 3.14159265358979323846
#endif

#define HOP 160
#define NBM 1024        // mean-reduction stage-1 blocks
#define NBLK_MAX 1024   // stft blocks

__device__ __forceinline__ float wave_reduce(float v) {
    for (int off = 32; off > 0; off >>= 1) v += __shfl_down(v, off, 64);
    return v;
}

// 8-point complex DFT in registers, natural order, W8 = exp(-i*pi/4).
__device__ __forceinline__ void dft8(float* xr, float* xi) {
    const float s = 0.70710678118654752440f;
    float t0r = xr[0] + xr[4], t0i = xi[0] + xi[4];
    float t1r = xr[0] - xr[4], t1i = xi[0] - xi[4];
    float t2r = xr[2] + xr[6], t2i = xi[2] + xi[6];
    float t3r = xr[2] - xr[6], t3i = xi[2] - xi[6];
    float E0r = t0r + t2r, E0i = t0i + t2i;
    float E2r = t0r - t2r, E2i = t0i - t2i;
    float E1r = t1r + t3i, E1i = t1i - t3r;
    float E3r = t1r - t3i, E3i = t1i + t3r;
    float u0r = xr[1] + xr[5], u0i = xi[1] + xi[5];
    float u1r = xr[1] - xr[5], u1i = xi[1] - xi[5];
    float u2r = xr[3] + xr[7], u2i = xi[3] + xi[7];
    float u3r = xr[3] - xr[7], u3i = xi[3] - xi[7];
    float O0r = u0r + u2r, O0i = u0i + u2i;
    float O2r = u0r - u2r, O2i = u0i - u2i;
    float O1r = u1r + u3i, O1i = u1i - u3r;
    float O3r = u1r - u3i, O3i = u1i + u3r;
    float T1r = s * (O1r + O1i), T1i = s * (O1i - O1r);
    float T2r = O2i,             T2i = -O2r;
    float T3r = s * (O3i - O3r), T3i = -s * (O3r + O3i);
    xr[0] = E0r + O0r; xi[0] = E0i + O0i;
    xr[4] = E0r - O0r; xi[4] = E0i - O0i;
    xr[1] = E1r + T1r; xi[1] = E1i + T1i;
    xr[5] = E1r - T1r; xi[5] = E1i - T1i;
    xr[2] = E2r + T2r; xi[2] = E2i + T2i;
    xr[6] = E2r - T2r; xi[6] = E2i - T2i;
    xr[3] = E3r + T3r; xi[3] = E3i + T3i;
    xr[7] = E3r - T3r; xi[7] = E3i - T3i;
}

__device__ __forceinline__ void cmul_t(float& zr, float& zi, float tr, float ti) {
    float r = zr * tr - zi * ti;
    float i = zr * ti + zi * tr;
    zr = r; zi = i;
}

// striped SoA LDS map: complex slot i -> re at a, im at a+128 (256-float stripes)
__device__ __forceinline__ int stripe(int i) {
    return ((i >> 7) << 8) | (i & 127);
}

// ---------------- stage 1: per-block partial sums for channel means --------
__global__ __launch_bounds__(256) void mean_partial_kernel(
        const float* __restrict__ x0, const float* __restrict__ x1,
        float* __restrict__ part, int n, int nbm)
{
    int tid = threadIdx.x;
    float s0 = 0.f, s1 = 0.f;
    int n4 = n >> 2;
    const float4* x04 = (const float4*)x0;
    const float4* x14 = (const float4*)x1;
    for (int i = blockIdx.x * blockDim.x + tid; i < n4; i += blockDim.x * gridDim.x) {
        float4 a = x04[i], b = x14[i];
        s0 += (a.x + a.y) + (a.z + a.w);
        s1 += (b.x + b.y) + (b.z + b.w);
    }
    __shared__ float red[4][2];
    s0 = wave_reduce(s0); s1 = wave_reduce(s1);
    int lane = tid & 63, w = tid >> 6;
    if (lane == 0) { red[w][0] = s0; red[w][1] = s1; }
    __syncthreads();
    if (tid == 0) {
        part[blockIdx.x]       = red[0][0] + red[1][0] + red[2][0] + red[3][0];
        part[nbm + blockIdx.x] = red[0][1] + red[1][1] + red[2][1] + red[3][1];
    }
}

// ---------------- stage 2: finish means + build twiddle table --------------
// twd layout (float index j*64 + l):  [0..7]=win, [8..15]=t1r, [16..23]=t1i,
// [24..31]=t2r, [32..39]=t2i
__global__ __launch_bounds__(256) void mean_final_kernel(
        const float* __restrict__ part, float* __restrict__ means,
        float* __restrict__ twd, int n, int nbm)
{
    int tid = threadIdx.x;
    float v0 = 0.f, v1 = 0.f;
    for (int i = tid; i < nbm; i += 256) { v0 += part[i]; v1 += part[nbm + i]; }
    __shared__ float red[4][2];
    v0 = wave_reduce(v0); v1 = wave_reduce(v1);
    int lane = tid & 63, w = tid >> 6;
    if (lane == 0) { red[w][0] = v0; red[w][1] = v1; }
    __syncthreads();
    if (tid == 0) {
        float s0 = red[0][0] + red[1][0] + red[2][0] + red[3][0];
        float s1 = red[0][1] + red[1][1] + red[2][1] + red[3][1];
        float inv = 1.0f / ((float)n * 32768.0f);
        means[0] = s0 * inv;
        means[1] = s1 * inv;
    }
    if (tid < 64) {
        int l = tid, hi = l >> 3;
        for (int j = 0; j < 8; ++j) {
            twd[j * 64 + l] = 0.5f - 0.5f * cosf((float)(2.0 * M_PI / 512.0) * (float)(l + 64 * j));
            float c1, s1v, c2, s2v;
            sincosf((float)(-2.0 * M_PI / 64.0) * (float)(j * hi), &s1v, &c1);
            sincosf((float)(-2.0 * M_PI / 512.0) * (float)(j * l), &s2v, &c2);
            twd[(8 + j) * 64 + l]  = c1;
            twd[(16 + j) * 64 + l] = s1v;
            twd[(24 + j) * 64 + l] = c2;
            twd[(32 + j) * 64 + l] = s2v;
        }
    }
}

// ---------------- stage 3: STFT (wave-local FFT) + covariance --------------
// Each wave independently processes frames f0+w, f0+w+4, ... No barriers in
// the frame loop (wave-private LDS buffers). Accumulates A_k = sum wt|Z_k|^2
// (all 8 regs) and W_k = sum wt Z_k Z_{N-k} (r<4 + Nyquist); R formed at end.
__global__ __launch_bounds__(256, 4) void stft_fft_kernel(
        const float* __restrict__ x0, const float* __restrict__ x1,
        const float* __restrict__ means, const float* __restrict__ twd,
        float* __restrict__ partials,
        int nframes, int fpb, int nblocks, float invS, float kslope)
{
    __shared__ float smem[4160];   // 4 waves x 1024 FFT bufs; reused as [4][1028]
    const int tid = threadIdx.x;
    const int w = tid >> 6, l = tid & 63;
    float* buf = smem + w * 1024;
    const int n0 = l & 7, hi = l >> 3;
    const int pl = (64 - l) & 63;

    // load per-lane constants from table (L2-resident)
    float winv[8], t1r[8], t1i[8], t2r[8], t2i[8];
#pragma unroll
    for (int j = 0; j < 8; ++j) {
        winv[j] = twd[j * 64 + l];
        t1r[j]  = twd[(8 + j) * 64 + l];
        t1i[j]  = twd[(16 + j) * 64 + l];
        t2r[j]  = twd[(24 + j) * 64 + l];
        t2i[j]  = twd[(32 + j) * 64 + l];
    }
    const float m0 = means[0], m1 = means[1];
    const float cm0 = 0.03f * m0, cm1 = 0.03f * m1;
    const float k15 = 1.0f / 32768.0f;

    float A[8];
    float Wr[5], Wi[5];
#pragma unroll
    for (int r = 0; r < 8; ++r) A[r] = 0.f;
#pragma unroll
    for (int r = 0; r < 5; ++r) { Wr[r] = 0.f; Wi[r] = 0.f; }

    int f0 = blockIdx.x * fpb;
    int f1 = f0 + fpb; if (f1 > nframes) f1 = nframes;

    for (int f = f0 + w; f < f1; f += 4) {
        int base = f * HOP;
        float wt = expf(fmaf(kslope, (float)f, -2.0f)) * invS;

        float zr[8], zi[8];
#pragma unroll
        for (int j = 0; j < 8; ++j) {
            int t = base + l + 64 * j;
            int tp = t - 1;
            if (j == 0) tp = (tp < 0) ? 0 : tp;   // n=0 sample is windowed to 0 anyway
            float d0 = fmaf(-0.97f, x0[tp], x0[t]);
            float d1 = fmaf(-0.97f, x1[tp], x1[t]);
            float y0 = fmaf(d0, k15, -cm0);
            float y1 = fmaf(d1, k15, -cm1);
            zr[j] = y0 * winv[j];
            zi[j] = y1 * winv[j];
        }

        dft8(zr, zi);   // over n2 -> regs k2

        // T1: element (n0,n1,k2) at slot i = (l ^ (k2<<3)) + 64*k2
#pragma unroll
        for (int k2 = 0; k2 < 8; ++k2) {
            int a = stripe((l ^ (k2 << 3)) + 64 * k2);
            buf[a] = zr[k2]; buf[a + 128] = zi[k2];
        }
#pragma unroll
        for (int j = 0; j < 8; ++j) {   // read reg n1=j: lane role (n0, k2=hi)
            int a = stripe(n0 + 8 * (j ^ hi) + 64 * hi);
            zr[j] = buf[a]; zi[j] = buf[a + 128];
        }
#pragma unroll
        for (int j = 1; j < 8; ++j) cmul_t(zr[j], zi[j], t1r[j], t1i[j]);
        dft8(zr, zi);   // over n1 -> regs k1

        // T2: element (n0,k2,k1) at slot i = k2 + 8*(k1^n0) + 64*n0
#pragma unroll
        for (int k1 = 0; k1 < 8; ++k1) {
            int a = stripe(hi + 8 * ((k1 ^ n0) + 8 * n0));
            buf[a] = zr[k1]; buf[a + 128] = zi[k1];
        }
#pragma unroll
        for (int j = 0; j < 8; ++j) {   // read reg n0=j: lane role (k2=n0, k1=hi)
            int a = stripe(n0 + 8 * ((hi ^ j) + 8 * j));
            zr[j] = buf[a]; zi[j] = buf[a + 128];
        }
#pragma unroll
        for (int j = 1; j < 8; ++j) cmul_t(zr[j], zi[j], t2r[j], t2i[j]);
        dft8(zr, zi);   // over n0 -> Z[l + 64*k0] in regs k0

        // A_k += wt*|Z_k|^2  (lane-local, all 8 regs)
#pragma unroll
        for (int r = 0; r < 8; ++r) {
            float u = fmaf(zr[r], zr[r], zi[r] * zi[r]);
            A[r] = fmaf(wt, u, A[r]);
        }
        // W_k += wt * Z_k * Z_{512-k} for k = l+64r, r<4 (partner via shuffle)
#pragma unroll
        for (int r = 0; r < 4; ++r) {
            float br = __shfl(zr[7 - r], pl, 64);
            float bi = __shfl(zi[7 - r], pl, 64);
            if (l == 0) { br = zr[(8 - r) & 7]; bi = zi[(8 - r) & 7]; }
            float wr = fmaf(zr[r], br, -(zi[r] * bi));
            float wi = fmaf(zr[r], bi, zi[r] * br);
            Wr[r] = fmaf(wt, wr, Wr[r]);
            Wi[r] = fmaf(wt, wi, Wi[r]);
        }
        {   // Nyquist bin 256 (lane 0's reg 4; computed uniformly, used on lane 0)
            float wr = fmaf(zr[4], zr[4], -(zi[4] * zi[4]));
            float wi = 2.f * zr[4] * zi[4];
            Wr[4] = fmaf(wt, wr, Wr[4]);
            Wi[4] = fmaf(wt, wi, Wi[4]);
        }
    }

    // form R per lane:  R00=(A+A'+2Wr)/4, R11=(A+A'-2Wr)/4, R01r=Wi/2, R01i=(A-A')/4
    float R00[4], R11[4], R01r[4], R01i[4];
#pragma unroll
    for (int r = 0; r < 4; ++r) {
        float ap = __shfl(A[7 - r], pl, 64);
        if (l == 0) ap = A[(8 - r) & 7];
        R00[r]  = 0.25f * (A[r] + ap + 2.f * Wr[r]);
        R11[r]  = 0.25f * (A[r] + ap - 2.f * Wr[r]);
        R01r[r] = 0.5f  * Wi[r];
        R01i[r] = 0.25f * (A[r] - ap);
    }

    // block-level reduce across 4 waves via LDS (reuse smem as [4][1028])
    __syncthreads();
    float (*red)[1028] = (float (*)[1028])smem;
#pragma unroll
    for (int r = 0; r < 4; ++r) {
        int k = l + 64 * r;
        red[w][0 * 257 + k] = R00[r];
        red[w][1 * 257 + k] = R11[r];
        red[w][2 * 257 + k] = R01r[r];
        red[w][3 * 257 + k] = R01i[r];
    }
    if (l == 0) {
        red[w][0 * 257 + 256] = 0.5f * (A[4] + Wr[4]);
        red[w][1 * 257 + 256] = 0.5f * (A[4] - Wr[4]);
        red[w][2 * 257 + 256] = 0.5f * Wi[4];
        red[w][3 * 257 + 256] = 0.f;
    }
    __syncthreads();
    for (int s = tid; s < 1028; s += 256) {
        float v = (red[0][s] + red[1][s]) + (red[2][s] + red[3][s]);
        partials[(size_t)s * nblocks + blockIdx.x] = v;
    }
}

// ---------------- stage 4: reduce partials over blocks ---------------------
__global__ __launch_bounds__(256) void reduce_kernel(
        const float* __restrict__ partials, float* __restrict__ R, int nblocks)
{
    int s = blockIdx.x;   // 0..1027
    int tid = threadIdx.x, lane = tid & 63, w = tid >> 6;
    const float* p = partials + (size_t)s * nblocks;
    float v = 0.f;
    for (int i = tid; i < nblocks; i += 256) v += p[i];
    __shared__ float red[4];
    v = wave_reduce(v);
    if (lane == 0) red[w] = v;
    __syncthreads();
    if (tid == 0) R[s] = (red[0] + red[1]) + (red[2] + red[3]);
}

// ---------------- stage 5: per-angle MVDR scores (181 blocks x 1 wave) -----
__global__ __launch_bounds__(64) void score_kernel(
        const float* __restrict__ R, float* __restrict__ scores)
{
    int a = blockIdx.x;          // angle 0..180
    int l = threadIdx.x;         // lane 0..63

    float rad = (float)a * (float)(M_PI / 180.0);
    float tau = -(0.05f * cosf(rad)) / 343.0f;
    float t2  = (float)(2.0 * M_PI) * tau;

    float fwsum = 0.f;
    float geo = 0.f, ari = 0.f;
    float m = -1e30f, se = 0.f, pe = 0.f;

    // lane handles bins l, l+64, l+128, l+192; lane 0 also bin 256
    for (int q = 0; q < 5; ++q) {
        int kk = l + 64 * q;
        if (kk > 256) break;
        float R00  = R[0 * 257 + kk];
        float R11  = R[1 * 257 + kk];
        float R01r = R[2 * 257 + kk];
        float R01i = R[3 * 257 + kk];
        float trace = (R00 + R11) * 0.5f;
        float det = R00 * R11 - (R01r * R01r + R01i * R01i) + 1e-6f * trace;
        float inv_det = 1.0f / det;
        float Sd = (R11 + R00) * inv_det;
        float qr = -R01r * inv_det;
        float qi = -R01i * inv_det;

        float fq = 31.25f * (float)kk;
        float wl = 343.0f / (fq + 1e-6f);
        float sr = 0.05f / wl;
        float spatial = 1.0f / (1.0f + expf(-4.0f * (sr - 0.1f)));
        float d = fq - (float)(16000.0 / 6.0);
        float fwq = 1.0f - expf(-(d * d) / (float)(2.0 * 4000.0 * 4000.0));
        float alias = (sr < 0.5f) ? 1.0f : expf(-2.0f * (sr - 0.5f) * (sr - 0.5f));
        float fw = spatial * fwq * alias;
        fwsum += fw;

        float cr, ci;
        sincosf(t2 * fq, &ci, &cr);
        float t  = qr * cr + qi * ci;
        float qf = Sd + t + t;
        float mv = 1.0f / (qf + 1e-6f);

        geo = fmaf(logf(mv + 1e-6f), fw, geo);
        ari = fmaf(mv, fw, ari);
        float x = mv + mv;
        if (x > m) {
            float sc = expf(m - x);
            se = fmaf(se, sc, 1.0f);
            pe = fmaf(pe, sc, mv * fw);
            m = x;
        } else {
            float e = expf(x - m);
            se += e;
            pe = fmaf(mv * fw, e, pe);
        }
    }

    // butterfly reduce: fwsum/geo/ari sums + online-softmax triple merge
    for (int off = 1; off < 64; off <<= 1) {
        fwsum += __shfl_xor(fwsum, off, 64);
        geo   += __shfl_xor(geo, off, 64);
        ari   += __shfl_xor(ari, off, 64);
        float mo = __shfl_xor(m, off, 64);
        float so = __shfl_xor(se, off, 64);
        float po = __shfl_xor(pe, off, 64);
        float mm = fmaxf(m, mo);
        float c1 = expf(m - mm), c2 = expf(mo - mm);
        se = fmaf(se, c1, so * c2);
        pe = fmaf(pe, c1, po * c2);
        m = mm;
    }
    if (l == 0) {
        float invcw = 1.0f / (fwsum + 1e-6f);
        float geon = geo * invcw;
        float arin = ari * invcw;
        float peak = (pe * invcw) / se;
        scores[a] = 0.5f * expf(geon) + 0.3f * arin + 0.2f * peak;
    }
}

// ---------------- stage 6: argmax over 181 scores --------------------------
__global__ __launch_bounds__(256) void argmax_kernel(
        const float* __restrict__ scores, float* __restrict__ out)
{
    int tid = threadIdx.x, lane = tid & 63, w = tid >> 6;
    float v = (tid < 181) ? scores[tid] : -1e30f;
    int   i = tid;
    for (int off = 1; off < 64; off <<= 1) {
        float vo = __shfl_xor(v, off, 64);
        int   io = __shfl_xor(i, off, 64);
        if (vo > v || (vo == v && io < i)) { v = vo; i = io; }
    }
    __shared__ float rv[4];
    __shared__ int   ri[4];
    if (lane == 0) { rv[w] = v; ri[w] = i; }
    __syncthreads();
    if (tid == 0) {
        float bv = rv[0]; int bi = ri[0];
        for (int q = 1; q < 4; ++q) {
            if (rv[q] > bv || (rv[q] == bv && ri[q] < bi)) { bv = rv[q]; bi = ri[q]; }
        }
        out[0] = (float)bi;
    }
}

extern "C" void kernel_launch(void* const* d_in, const int* in_sizes, int n_in,
                              void* d_out, int out_size, void* d_ws, size_t ws_size,
                              hipStream_t stream) {
    const float* x0 = (const float*)d_in[0];
    const float* x1 = (const float*)d_in[1];
    float* out = (float*)d_out;
    int T = in_sizes[0];
    int nframes = (T - 512) / HOP + 1;

    // TEMPORAL normalization: sum over all 40000 entries (host, double)
    double S = 0.0;
    for (int j = 0; j < 40000; ++j) S += exp(-2.0 + 2.0 * (double)j / 39999.0);
    float invS = (float)(1.0 / S);
    float kslope = (float)(2.0 / 39999.0);

    float* ws = (float*)d_ws;
    float* means    = ws;            // 2
    float* twd      = ws + 64;       // 2560
    float* mpart    = ws + 4096;     // 2*NBM = 2048
    float* Rbuf     = ws + 8192;     // 1028
    float* scores   = ws + 9472;     // 181
    float* partials = ws + 16384;    // 1028 * nblocks

    long availf = (long)(ws_size / 4) - 16384;
    int nblocks = (int)(availf / 1028);
    if (nblocks > NBLK_MAX) nblocks = NBLK_MAX;
    if (nblocks < 1) nblocks = 1;
    int fpb = (nframes + nblocks - 1) / nblocks;

    mean_partial_kernel<<<NBM, 256, 0, stream>>>(x0, x1, mpart, T, NBM);
    mean_final_kernel<<<1, 256, 0, stream>>>(mpart, means, twd, T, NBM);
    stft_fft_kernel<<<nblocks, 256, 0, stream>>>(x0, x1, means, twd, partials,
                                                 nframes, fpb, nblocks, invS, kslope);
    reduce_kernel<<<1028, 256, 0, stream>>>(partials, Rbuf, nblocks);
    score_kernel<<<181, 64, 0, stream>>>(Rbuf, scores);
    argmax_kernel<<<1, 256, 0, stream>>>(scores, out);
}